// Round 1
// 996.719 us; speedup vs baseline: 1.2363x; 1.2363x over previous
//
#include <hip/hip_runtime.h>

#define NTOK 32768
#define HD   4096
#define EXP  64
#define KCAP 512
#define CAP  2048
#define KSPLIT 4

static __device__ __forceinline__ unsigned f2key(float f) {
  unsigned b = __float_as_uint(f);
  return (b & 0x80000000u) ? ~b : (b ^ 0x80000000u);
}

// ---------------- GEMM: out[N,64] (+= over K chunk) = x[N,4096] @ W[4096,64] ----
// grid = (NTOK/64, KS). Each block: 64 rows x 64 cols over K chunk HD/KS.
// KS=4 -> 2048 blocks = 8 blocks/CU = 32 waves/CU (100% occupancy).
// W via wave-uniform (scalar) loads -> SGPRs; x staged transposed in LDS.
__global__ __launch_bounds__(256) void gemm_kernel(const float* __restrict__ x,
                                                   const float* __restrict__ Wg,
                                                   float* __restrict__ out,
                                                   float* __restrict__ logitsT,
                                                   const int writeT) {
  __shared__ float xs[64][65];   // [k][m], pad -> 2-way bank aliasing (free)
  const int tid  = threadIdx.x;
  const int lane = tid & 63;
  const int wv   = tid >> 6;
  // force wave-uniform column base so W loads scalarize to s_load
  const int n0   = __builtin_amdgcn_readfirstlane(wv << 4);
  const int mbase = blockIdx.x * 64;
  const int klen  = HD / gridDim.y;
  const int kbeg  = blockIdx.y * klen;
  const int kend  = kbeg + klen;
  float* __restrict__ obase = out + (size_t)blockIdx.y * ((size_t)NTOK * EXP);

  float acc[16];
#pragma unroll
  for (int j = 0; j < 16; ++j) acc[j] = 0.f;

  const int lr = tid >> 4;   // 0..15
  const int lc = tid & 15;   // float4 slot

  for (int kb = kbeg; kb < kend; kb += 64) {
    __syncthreads();
#pragma unroll
    for (int p = 0; p < 4; ++p) {
      const int row = lr + p * 16;
      const float4 v = *(const float4*)(x + (size_t)(mbase + row) * HD + kb + lc * 4);
      xs[lc * 4 + 0][row] = v.x;
      xs[lc * 4 + 1][row] = v.y;
      xs[lc * 4 + 2][row] = v.z;
      xs[lc * 4 + 3][row] = v.w;
    }
    __syncthreads();

#pragma unroll 4
    for (int kk = 0; kk < 64; ++kk) {
      const float xv = xs[kk][lane];
      const float* __restrict__ wr = Wg + (size_t)(kb + kk) * 64 + n0;  // wave-uniform
      const float4 w0 = *(const float4*)(wr);
      const float4 w1 = *(const float4*)(wr + 4);
      const float4 w2 = *(const float4*)(wr + 8);
      const float4 w3 = *(const float4*)(wr + 12);
      acc[0]  = fmaf(xv, w0.x, acc[0]);
      acc[1]  = fmaf(xv, w0.y, acc[1]);
      acc[2]  = fmaf(xv, w0.z, acc[2]);
      acc[3]  = fmaf(xv, w0.w, acc[3]);
      acc[4]  = fmaf(xv, w1.x, acc[4]);
      acc[5]  = fmaf(xv, w1.y, acc[5]);
      acc[6]  = fmaf(xv, w1.z, acc[6]);
      acc[7]  = fmaf(xv, w1.w, acc[7]);
      acc[8]  = fmaf(xv, w2.x, acc[8]);
      acc[9]  = fmaf(xv, w2.y, acc[9]);
      acc[10] = fmaf(xv, w2.z, acc[10]);
      acc[11] = fmaf(xv, w2.w, acc[11]);
      acc[12] = fmaf(xv, w3.x, acc[12]);
      acc[13] = fmaf(xv, w3.y, acc[13]);
      acc[14] = fmaf(xv, w3.z, acc[14]);
      acc[15] = fmaf(xv, w3.w, acc[15]);
    }
  }

  float* orow = obase + (size_t)(mbase + lane) * 64 + n0;
  *(float4*)(orow + 0)  = make_float4(acc[0], acc[1], acc[2], acc[3]);
  *(float4*)(orow + 4)  = make_float4(acc[4], acc[5], acc[6], acc[7]);
  *(float4*)(orow + 8)  = make_float4(acc[8], acc[9], acc[10], acc[11]);
  *(float4*)(orow + 12) = make_float4(acc[12], acc[13], acc[14], acc[15]);

  if (writeT) {   // only used in the single-chunk fallback path
#pragma unroll
    for (int j = 0; j < 16; ++j)
      logitsT[(size_t)(n0 + j) * NTOK + mbase + lane] = acc[j];   // coalesced
  }
}

// ---------------- reduce KSPLIT partials -> logits + logitsT (tiled transpose) ----
// grid = NTOK/64 blocks x 256 threads. Block handles 64 tokens x 64 experts.
__global__ __launch_bounds__(256) void reduce_kernel(const float* __restrict__ part,
                                                     float* __restrict__ logits,
                                                     float* __restrict__ logitsT) {
  __shared__ float ls[64][65];   // [t][e]; stride 65 -> conflict-free col reads
  const int tid = threadIdx.x;
  const int t0  = blockIdx.x * 64;
  const int c4  = (tid & 15) * 4;   // expert float4 slot
  const int r0  = tid >> 4;         // 0..15

#pragma unroll
  for (int rep = 0; rep < 4; ++rep) {
    const int row = rep * 16 + r0;
    const size_t off = (size_t)(t0 + row) * 64 + c4;
    const float4 a = *(const float4*)(part + off);
    const float4 b = *(const float4*)(part + (size_t)1 * NTOK * EXP + off);
    const float4 c = *(const float4*)(part + (size_t)2 * NTOK * EXP + off);
    const float4 d = *(const float4*)(part + (size_t)3 * NTOK * EXP + off);
    float4 s;
    s.x = (a.x + b.x) + (c.x + d.x);
    s.y = (a.y + b.y) + (c.y + d.y);
    s.z = (a.z + b.z) + (c.z + d.z);
    s.w = (a.w + b.w) + (c.w + d.w);
    *(float4*)(logits + off) = s;
    ls[row][c4 + 0] = s.x;
    ls[row][c4 + 1] = s.y;
    ls[row][c4 + 2] = s.z;
    ls[row][c4 + 3] = s.w;
  }
  __syncthreads();

  const int lane = tid & 63;
  const int wvv  = tid >> 6;
#pragma unroll
  for (int j = 0; j < 16; ++j) {
    const int e = wvv * 16 + j;
    logitsT[(size_t)e * NTOK + t0 + lane] = ls[lane][e];   // coalesced 256B stores
  }
}

// ---------------- per-expert exact top-512 threshold, all in LDS ----------------
// 64 blocks (one per expert) x 1024 threads (16 waves -> latency hiding).
// Two passes over the expert's column with explicit 4-deep load batching,
// 256-bin hist -> bin select -> in-bin compaction -> 24-bit radix refine -> ties.
__global__ __launch_bounds__(1024) void topk_kernel(const float* __restrict__ colbase,
                                                    const long long cstride,
                                                    float* __restrict__ tau,
                                                    int* __restrict__ cutoff) {
  __shared__ int hist[256];
  __shared__ unsigned ckey[CAP];
  __shared__ int cidx[CAP];
  __shared__ int s_sel, s_above, s_cnt, s_m, s_eqcnt;
  __shared__ int eqidx[128];
  const int tid = threadIdx.x;
  const int e = blockIdx.x;
  const float* __restrict__ col =
      colbase + (cstride == 1 ? (long long)e * NTOK : (long long)e);

  if (tid < 256) hist[tid] = 0;
  if (tid == 0) { s_cnt = 0; s_eqcnt = 0; }
  __syncthreads();

  // pass 1: 256-bin histogram of top-8 key bits (batched loads, 8 outer iters)
  for (int i0 = tid; i0 < NTOK; i0 += 4096) {
    const unsigned k0 = f2key(col[(long long)(i0       ) * cstride]);
    const unsigned k1 = f2key(col[(long long)(i0 + 1024) * cstride]);
    const unsigned k2 = f2key(col[(long long)(i0 + 2048) * cstride]);
    const unsigned k3 = f2key(col[(long long)(i0 + 3072) * cstride]);
    atomicAdd(&hist[k0 >> 24], 1);
    atomicAdd(&hist[k1 >> 24], 1);
    atomicAdd(&hist[k2 >> 24], 1);
    atomicAdd(&hist[k3 >> 24], 1);
  }
  __syncthreads();
  if (tid == 0) {
    int cum = 0, sel = 0, ab = 0;
    for (int b = 255; b >= 0; --b) {            // no break -> pipelined LDS reads
      const int h = hist[b]; const int nc = cum + h;
      if (cum < KCAP && nc >= KCAP) { sel = b; ab = cum; }
      cum = nc;
    }
    s_sel = sel; s_above = ab;
  }
  __syncthreads();
  const int selbin = s_sel;
  int m = KCAP - s_above;                       // rank within selected bin, >=1

  // pass 2: compact in-bin candidates to LDS (batched loads)
  for (int i0 = tid; i0 < NTOK; i0 += 4096) {
    const unsigned k0 = f2key(col[(long long)(i0       ) * cstride]);
    const unsigned k1 = f2key(col[(long long)(i0 + 1024) * cstride]);
    const unsigned k2 = f2key(col[(long long)(i0 + 2048) * cstride]);
    const unsigned k3 = f2key(col[(long long)(i0 + 3072) * cstride]);
    if ((int)(k0 >> 24) == selbin) {
      const int p = atomicAdd(&s_cnt, 1);
      if (p < CAP) { ckey[p] = k0; cidx[p] = i0; }
    }
    if ((int)(k1 >> 24) == selbin) {
      const int p = atomicAdd(&s_cnt, 1);
      if (p < CAP) { ckey[p] = k1; cidx[p] = i0 + 1024; }
    }
    if ((int)(k2 >> 24) == selbin) {
      const int p = atomicAdd(&s_cnt, 1);
      if (p < CAP) { ckey[p] = k2; cidx[p] = i0 + 2048; }
    }
    if ((int)(k3 >> 24) == selbin) {
      const int p = atomicAdd(&s_cnt, 1);
      if (p < CAP) { ckey[p] = k3; cidx[p] = i0 + 3072; }
    }
  }
  __syncthreads();
  const int n = min(s_cnt, CAP);

  // radix refine remaining 24 bits
  unsigned prefix = ((unsigned)selbin) << 24;
  unsigned mask = 0xFF000000u;
  for (int shift = 16; shift >= 0; shift -= 8) {
    __syncthreads();
    if (tid < 256) hist[tid] = 0;
    __syncthreads();
    for (int i = tid; i < n; i += 1024) {
      const unsigned k = ckey[i];
      if ((k & mask) == prefix) atomicAdd(&hist[(k >> shift) & 0xFFu], 1);
    }
    __syncthreads();
    if (tid == 0) {
      int cum = 0, sel = 0, ab = 0;
      for (int b = 255; b >= 0; --b) {
        const int h = hist[b]; const int nc = cum + h;
        if (cum < m && nc >= m) { sel = b; ab = cum; }
        cum = nc;
      }
      s_sel = sel; s_m = m - ab;
    }
    __syncthreads();
    prefix |= ((unsigned)s_sel) << shift;
    mask   |= 0xFFu << shift;
    m = s_m;
  }

  // ties: accept the m smallest token indices among keys == prefix
  __syncthreads();
  for (int i = tid; i < n; i += 1024) {
    if (ckey[i] == prefix) {
      const int p = atomicAdd(&s_eqcnt, 1);
      if (p < 128) eqidx[p] = cidx[i];
    }
  }
  __syncthreads();
  if (tid == 0) {
    int cut = NTOK;                             // all ties accepted
    const int c = min(s_eqcnt, 128);
    if (s_eqcnt > m) {
      for (int i = 0; i < c; ++i) {
        int r = 0;
        for (int j = 0; j < c; ++j) r += (eqidx[j] <= eqidx[i]) ? 1 : 0;
        if (r == m) { cut = eqidx[i]; break; }
      }
    }
    cutoff[e] = cut;
    const unsigned kk = prefix;
    const unsigned b = (kk & 0x80000000u) ? (kk ^ 0x80000000u) : ~kk;
    tau[e] = __uint_as_float(b);
  }
}

// ---------------- assignment: one wave per token ----------------
__global__ __launch_bounds__(256) void assign_kernel(const float* __restrict__ logits,
                                                     const float* __restrict__ tau,
                                                     const int* __restrict__ cutoff,
                                                     float* __restrict__ wout,
                                                     float* __restrict__ iout) {
  const int gt = blockIdx.x * 256 + threadIdx.x;
  const int t = gt >> 6;
  const int lane = threadIdx.x & 63;
  const float v = logits[(size_t)t * 64 + lane];
  const float te = tau[lane];
  const int co = cutoff[lane];
  const bool picked = (v > te) || (v == te && t <= co);

  float fv = v;                       int fe = lane;        // fallback argmax (first max)
  float av = picked ? v : -INFINITY;  int ae = picked ? lane : 64;
#pragma unroll
  for (int off = 32; off > 0; off >>= 1) {
    const float ofv = __shfl_xor(fv, off);
    const int   ofe = __shfl_xor(fe, off);
    if (ofv > fv || (ofv == fv && ofe < fe)) { fv = ofv; fe = ofe; }
    const float oav = __shfl_xor(av, off);
    const int   oae = __shfl_xor(ae, off);
    if (oav > av || (oav == av && oae < ae)) { av = oav; ae = oae; }
  }
  if (lane == 0) {
    float w; int ei;
    if (ae < 64) { w = av; ei = ae; }
    else         { w = fv; ei = fe; }
    wout[t] = w;
    iout[t] = (float)ei;
  }
}

extern "C" void kernel_launch(void* const* d_in, const int* in_sizes, int n_in,
                              void* d_out, int out_size, void* d_ws, size_t ws_size,
                              hipStream_t stream) {
  const float* x  = (const float*)d_in[0];
  const float* Wg = (const float*)d_in[1];
  float* out    = (float*)d_out;
  float* wout   = out;
  float* iout   = out + NTOK;
  float* logits = out + 2 * NTOK;

  float* tau     = (float*)d_ws;
  int*   cutoff  = (int*)d_ws + 64;
  float* logitsT = (float*)d_ws + 256;
  float* part    = (float*)d_ws + 256 + (size_t)NTOK * EXP;

  const size_t needT = 256 * 4 + (size_t)NTOK * EXP * 4;
  const size_t needP = needT + (size_t)KSPLIT * NTOK * EXP * 4;
  const int useT  = (ws_size >= needT) ? 1 : 0;
  const int useKS = (ws_size >= needP) ? 1 : 0;

  if (useKS) {
    // K-split GEMM -> partials -> reduce (writes logits + logitsT)
    hipLaunchKernelGGL(gemm_kernel, dim3(NTOK / 64, KSPLIT), dim3(256), 0, stream,
                       x, Wg, part, logitsT, 0);
    hipLaunchKernelGGL(reduce_kernel, dim3(NTOK / 64), dim3(256), 0, stream,
                       part, logits, logitsT);
    hipLaunchKernelGGL(topk_kernel, dim3(EXP), dim3(1024), 0, stream,
                       (const float*)logitsT, 1LL, tau, cutoff);
  } else {
    // fallback: single-chunk GEMM (old path)
    hipLaunchKernelGGL(gemm_kernel, dim3(NTOK / 64, 1), dim3(256), 0, stream,
                       x, Wg, logits, logitsT, useT);
    hipLaunchKernelGGL(topk_kernel, dim3(EXP), dim3(1024), 0, stream,
                       useT ? (const float*)logitsT : (const float*)logits,
                       useT ? 1LL : 64LL, tau, cutoff);
  }
  hipLaunchKernelGGL(assign_kernel, dim3(NTOK / 4), dim3(256), 0, stream,
                     logits, tau, cutoff, wout, iout);
}